// Round 4
// baseline (336.486 us; speedup 1.0000x reference)
//
#include <hip/hip_runtime.h>

// TopKGate: x[16384,2048] fp32, Wg[2048,64] fp32 ->
//   gate_weights[T,64], top_idx[T,2] (as float), aux_loss (1 float)
//
// Zero-LDS / zero-barrier structure: 1-wave blocks, lane = expert.
// x rows are blockIdx-uniform -> scalar loads (SMEM pipe, SGPR operand to FMA).
// Wg columns per-lane in VGPRs, global-loaded (L2-resident), ping-pong dbuf.

constexpr int DD  = 2048;
constexpr int EE  = 64;
constexpr int DCH = 32;          // d-chunk held in VGPRs
constexpr int NCH = DD / DCH;    // 64 chunks
constexpr int TPB_TOK = 8;       // tokens per block (1 wave)

__global__ __launch_bounds__(64) void gate_kernel(
    const float* __restrict__ x, const float* __restrict__ Wg,
    float* __restrict__ gate_out, float* __restrict__ idx_out,
    float* __restrict__ pSum, float* __restrict__ pCnt)
{
    const int lane = threadIdx.x;            // = expert id (0..63)
    const size_t tok0 = (size_t)blockIdx.x * TPB_TOK;

    float acc[TPB_TOK];
#pragma unroll
    for (int i = 0; i < TPB_TOK; ++i) acc[i] = 0.f;

    float wA[DCH], wB[DCH];

    // per-lane Wg column chunk: coalesced dword loads, L2-resident
    auto loadW = [&](float* wbuf, int ci) {
        const float* wp = Wg + (size_t)ci * DCH * EE + lane;
#pragma unroll
        for (int dd = 0; dd < DCH; ++dd) wbuf[dd] = wp[(size_t)dd * EE];
    };

    // x is blockIdx-uniform -> s_load; one SGPR operand per FMA
    auto compute = [&](const float* wbuf, int ci) {
#pragma unroll
        for (int tt = 0; tt < TPB_TOK; ++tt) {
            const float4* xr = (const float4*)(x + (tok0 + tt) * DD + ci * DCH);
#pragma unroll
            for (int j = 0; j < DCH / 4; ++j) {
                float4 xv = xr[j];
                acc[tt] = fmaf(xv.x, wbuf[4 * j + 0], acc[tt]);
                acc[tt] = fmaf(xv.y, wbuf[4 * j + 1], acc[tt]);
                acc[tt] = fmaf(xv.z, wbuf[4 * j + 2], acc[tt]);
                acc[tt] = fmaf(xv.w, wbuf[4 * j + 3], acc[tt]);
            }
        }
    };

    loadW(wA, 0);
#pragma unroll 1
    for (int ci = 0; ci < NCH; ci += 2) {
        loadW(wB, ci + 1);                    // in flight over compute(wA)
        compute(wA, ci);
        if (ci + 2 < NCH) loadW(wA, ci + 2);  // in flight over compute(wB)
        compute(wB, ci + 1);
    }

    // ---- per-token softmax + top-2 (lane = expert) ----
    float sumP_acc = 0.f;
    float cnt_acc  = 0.f;
#pragma unroll 1
    for (int tt = 0; tt < TPB_TOK; ++tt) {
        const size_t t = tok0 + tt;
        float v = acc[tt];

        float m = v;
#pragma unroll
        for (int off = 32; off; off >>= 1) m = fmaxf(m, __shfl_xor(m, off, 64));
        float p = expf(v - m);
        float s = p;
#pragma unroll
        for (int off = 32; off; off >>= 1) s += __shfl_xor(s, off, 64);
        float prob = p / s;
        sumP_acc += prob;

        // top-1 (ties -> lowest index, matches lax.top_k)
        float bv = prob; int bi = lane;
#pragma unroll
        for (int off = 32; off; off >>= 1) {
            float ov = __shfl_xor(bv, off, 64);
            int   oi = __shfl_xor(bi, off, 64);
            if (ov > bv || (ov == bv && oi < bi)) { bv = ov; bi = oi; }
        }
        // top-2
        float v2 = (lane == bi) ? -1.f : prob;
        float bv2 = v2; int bi2 = lane;
#pragma unroll
        for (int off = 32; off; off >>= 1) {
            float ov = __shfl_xor(bv2, off, 64);
            int   oi = __shfl_xor(bi2, off, 64);
            if (ov > bv2 || (ov == bv2 && oi < bi2)) { bv2 = ov; bi2 = oi; }
        }

        float denom = bv + bv2;
        float g1 = bv / denom, g2 = bv2 / denom;
        float g = (lane == bi) ? g1 : ((lane == bi2) ? g2 : 0.f);
        gate_out[t * EE + lane] = g;
        if (lane == 0) {
            idx_out[2 * t]     = (float)bi;
            idx_out[2 * t + 1] = (float)bi2;
        }
        cnt_acc += (lane == bi)  ? 1.f : 0.f;
        cnt_acc += (lane == bi2) ? 1.f : 0.f;
    }

    // per-block (== per-wave) partials for aux loss; deterministic
    pSum[(size_t)blockIdx.x * 64 + lane] = sumP_acc;
    pCnt[(size_t)blockIdx.x * 64 + lane] = cnt_acc;
}

// parallel aux reduction: 1024 threads (16 waves), 4-deep ILP + LDS reduce
__global__ __launch_bounds__(1024) void aux_kernel(
    const float* __restrict__ pSum, const float* __restrict__ pCnt,
    float* __restrict__ aux_out, int nblocks, float scale)
{
    const int tid  = threadIdx.x;
    const int wv   = tid >> 6;       // 0..15
    const int lane = tid & 63;       // = expert id
    __shared__ float smem[2][16][64];

    float sp[4] = {0.f, 0.f, 0.f, 0.f};
    float cc[4] = {0.f, 0.f, 0.f, 0.f};
    for (int b = wv * 4; b < nblocks; b += 64) {
#pragma unroll
        for (int u = 0; u < 4; ++u) {
            sp[u] += pSum[(size_t)(b + u) * 64 + lane];
            cc[u] += pCnt[(size_t)(b + u) * 64 + lane];
        }
    }
    smem[0][wv][lane] = (sp[0] + sp[1]) + (sp[2] + sp[3]);
    smem[1][wv][lane] = (cc[0] + cc[1]) + (cc[2] + cc[3]);
    __syncthreads();
    if (wv == 0) {
        float SP = 0.f, C = 0.f;
#pragma unroll
        for (int w = 0; w < 16; ++w) {
            SP += smem[0][w][lane];
            C  += smem[1][w][lane];
        }
        float prod = SP * C;
#pragma unroll
        for (int off = 32; off; off >>= 1) prod += __shfl_xor(prod, off, 64);
        if (lane == 0) aux_out[0] = prod * scale;
    }
}

extern "C" void kernel_launch(void* const* d_in, const int* in_sizes, int n_in,
                              void* d_out, int out_size, void* d_ws, size_t ws_size,
                              hipStream_t stream) {
    const float* x  = (const float*)d_in[0];
    const float* Wg = (const float*)d_in[1];
    const int T = in_sizes[0] / DD;          // 16384

    float* out      = (float*)d_out;
    float* gate_out = out;                                // T*64
    float* idx_out  = out + (size_t)T * EE;               // T*2 (as float)
    float* aux_out  = idx_out + (size_t)T * 2;            // 1

    const int nblocks = T / TPB_TOK;                      // 2048
    float* pSum = (float*)d_ws;                           // nblocks*64
    float* pCnt = pSum + (size_t)nblocks * 64;            // nblocks*64

    gate_kernel<<<nblocks, 64, 0, stream>>>(x, Wg, gate_out, idx_out, pSum, pCnt);

    const float scale = (float)EE / ((float)T * (float)T);
    aux_kernel<<<1, 1024, 0, stream>>>(pSum, pCnt, aux_out, nblocks, scale);
}

// Round 5
// 278.933 us; speedup vs baseline: 1.2063x; 1.2063x over previous
//
#include <hip/hip_runtime.h>

// TopKGate: x[16384,2048] fp32, Wg[2048,64] fp32 ->
//   gate_weights[T,64], top_idx[T,2] (as float), aux_loss (1 float)
//
// Layout: lane = token (64 tokens/block), acc[64] experts per lane.
// K split 8 ways across the block's waves (wave w handles d in [w*256,(w+1)*256)).
// x: per-lane VGPR loads of own row, ping-pong prefetch, no LDS in main loop.
// Wg: wave-uniform rows -> scalar loads (k$/L2), SGPR operand to v_fmac.
// In-LDS pad-65 reduction of the 8 partial acc sets, then R3-style wave softmax.

constexpr int DD  = 2048;
constexpr int EE  = 64;
constexpr int TPB = 512;              // 8 waves
constexpr int TOK_PER_BLOCK = 64;     // lane = token
constexpr int KSPLIT = 8;
constexpr int KSLICE = DD / KSPLIT;   // 256
constexpr int DCH = 16;               // x chunk (floats) per register buffer
constexpr int NCH = KSLICE / DCH;     // 16 chunks

__global__ __launch_bounds__(TPB, 2) void gate_kernel(
    const float* __restrict__ x, const float* __restrict__ Wg,
    float* __restrict__ gate_out, float* __restrict__ idx_out,
    float* __restrict__ pSum, float* __restrict__ pCnt)
{
    const int tid  = threadIdx.x;
    const int lane = tid & 63;                                   // token-in-block (main), expert (epilogue)
    const int wv   = __builtin_amdgcn_readfirstlane(tid >> 6);   // wave id, known-uniform
    const size_t tok0 = (size_t)blockIdx.x * TOK_PER_BLOCK;

    float acc[EE];
#pragma unroll
    for (int e = 0; e < EE; ++e) acc[e] = 0.f;

    const int kbase = wv * KSLICE;                               // uniform
    const float* xp = x + (tok0 + lane) * DD + kbase;            // per-lane row slice

    // 16-dd dot: x scalar from VGPR, w row from uniform (scalar) loads
    auto dot16 = [&](const float4* xb, int dbase) {
#pragma unroll
        for (int dd = 0; dd < DCH; ++dd) {
            const float xd = ((const float*)xb)[dd];
            const float* wr = Wg + (size_t)(dbase + dd) * EE;    // uniform address
#pragma unroll
            for (int e = 0; e < EE; ++e)
                acc[e] = fmaf(xd, wr[e], acc[e]);
        }
    };

    float4 xA[4], xB[4];
    {
        const float4* nx = (const float4*)xp;
#pragma unroll
        for (int q = 0; q < 4; ++q) xA[q] = nx[q];
    }

#pragma unroll 1
    for (int c = 0; c < NCH; c += 2) {
        {   // prefetch chunk c+1 (always exists: c <= 14)
            const float4* nx = (const float4*)(xp + (c + 1) * DCH);
#pragma unroll
            for (int q = 0; q < 4; ++q) xB[q] = nx[q];
        }
        dot16(xA, kbase + c * DCH);
        if (c + 2 < NCH) {
            const float4* nx = (const float4*)(xp + (c + 2) * DCH);
#pragma unroll
            for (int q = 0; q < 4; ++q) xA[q] = nx[q];
        }
        dot16(xB, kbase + (c + 1) * DCH);
    }

    // ---- reduce 8 K-slice partials into LDS: red[e][t], pad 65 (conflict-free) ----
    __shared__ float red[EE][65];
#pragma unroll 1
    for (int w = 0; w < KSPLIT; ++w) {
        if (wv == w) {
            if (w == 0) {
#pragma unroll
                for (int e = 0; e < EE; ++e) red[e][lane] = acc[e];
            } else {
#pragma unroll
                for (int e = 0; e < EE; ++e) red[e][lane] += acc[e];
            }
        }
        __syncthreads();
    }

    // ---- epilogue: wave wv handles tokens [wv*8, wv*8+8); lane = expert ----
    float sumP_acc = 0.f;
    float cnt_acc  = 0.f;
#pragma unroll 1
    for (int tt = 0; tt < 8; ++tt) {
        const int tl = wv * 8 + tt;
        const size_t t = tok0 + tl;
        float v = red[lane][tl];          // (lane*65 + tl) -> 2-way bank alias, free

        float m = v;
#pragma unroll
        for (int off = 32; off; off >>= 1) m = fmaxf(m, __shfl_xor(m, off, 64));
        float p = expf(v - m);
        float s = p;
#pragma unroll
        for (int off = 32; off; off >>= 1) s += __shfl_xor(s, off, 64);
        float prob = p / s;
        sumP_acc += prob;

        // top-1 (ties -> lowest index, matches lax.top_k)
        float bv = prob; int bi = lane;
#pragma unroll
        for (int off = 32; off; off >>= 1) {
            float ov = __shfl_xor(bv, off, 64);
            int   oi = __shfl_xor(bi, off, 64);
            if (ov > bv || (ov == bv && oi < bi)) { bv = ov; bi = oi; }
        }
        // top-2
        float v2 = (lane == bi) ? -1.f : prob;
        float bv2 = v2; int bi2 = lane;
#pragma unroll
        for (int off = 32; off; off >>= 1) {
            float ov = __shfl_xor(bv2, off, 64);
            int   oi = __shfl_xor(bi2, off, 64);
            if (ov > bv2 || (ov == bv2 && oi < bi2)) { bv2 = ov; bi2 = oi; }
        }

        float denom = bv + bv2;
        float g1 = bv / denom, g2 = bv2 / denom;
        float g = (lane == bi) ? g1 : ((lane == bi2) ? g2 : 0.f);
        gate_out[t * EE + lane] = g;
        if (lane == 0) {
            idx_out[2 * t]     = (float)bi;
            idx_out[2 * t + 1] = (float)bi2;
        }
        cnt_acc += (lane == bi)  ? 1.f : 0.f;
        cnt_acc += (lane == bi2) ? 1.f : 0.f;
    }

    // ---- per-block aux partials ----
    __shared__ float auxsm[2][KSPLIT][64];
    auxsm[0][wv][lane] = sumP_acc;
    auxsm[1][wv][lane] = cnt_acc;
    __syncthreads();
    if (wv == 0) {
        float sp = 0.f, c = 0.f;
#pragma unroll
        for (int w = 0; w < KSPLIT; ++w) {
            sp += auxsm[0][w][lane];
            c  += auxsm[1][w][lane];
        }
        pSum[(size_t)blockIdx.x * 64 + lane] = sp;
        pCnt[(size_t)blockIdx.x * 64 + lane] = c;
    }
}

// parallel aux reduction: 1024 threads (16 waves), 4-deep ILP + LDS reduce
__global__ __launch_bounds__(1024) void aux_kernel(
    const float* __restrict__ pSum, const float* __restrict__ pCnt,
    float* __restrict__ aux_out, int nblocks, float scale)
{
    const int tid  = threadIdx.x;
    const int wv   = tid >> 6;       // 0..15
    const int lane = tid & 63;       // = expert id
    __shared__ float smem[2][16][64];

    float sp[4] = {0.f, 0.f, 0.f, 0.f};
    float cc[4] = {0.f, 0.f, 0.f, 0.f};
    for (int b = wv * 4; b < nblocks; b += 64) {
#pragma unroll
        for (int u = 0; u < 4; ++u) {
            sp[u] += pSum[(size_t)(b + u) * 64 + lane];
            cc[u] += pCnt[(size_t)(b + u) * 64 + lane];
        }
    }
    smem[0][wv][lane] = (sp[0] + sp[1]) + (sp[2] + sp[3]);
    smem[1][wv][lane] = (cc[0] + cc[1]) + (cc[2] + cc[3]);
    __syncthreads();
    if (wv == 0) {
        float SP = 0.f, C = 0.f;
#pragma unroll
        for (int w = 0; w < 16; ++w) {
            SP += smem[0][w][lane];
            C  += smem[1][w][lane];
        }
        float prod = SP * C;
#pragma unroll
        for (int off = 32; off; off >>= 1) prod += __shfl_xor(prod, off, 64);
        if (lane == 0) aux_out[0] = prod * scale;
    }
}

extern "C" void kernel_launch(void* const* d_in, const int* in_sizes, int n_in,
                              void* d_out, int out_size, void* d_ws, size_t ws_size,
                              hipStream_t stream) {
    const float* x  = (const float*)d_in[0];
    const float* Wg = (const float*)d_in[1];
    const int T = in_sizes[0] / DD;          // 16384

    float* out      = (float*)d_out;
    float* gate_out = out;                                // T*64
    float* idx_out  = out + (size_t)T * EE;               // T*2 (as float)
    float* aux_out  = idx_out + (size_t)T * 2;            // 1

    const int nblocks = T / TOK_PER_BLOCK;                // 256
    float* pSum = (float*)d_ws;                           // nblocks*64
    float* pCnt = pSum + (size_t)nblocks * 64;            // nblocks*64

    gate_kernel<<<nblocks, TPB, 0, stream>>>(x, Wg, gate_out, idx_out, pSum, pCnt);

    const float scale = (float)EE / ((float)T * (float)T);
    aux_kernel<<<1, 1024, 0, stream>>>(pSum, pCnt, aux_out, nblocks, scale);
}

// Round 6
// 113.393 us; speedup vs baseline: 2.9674x; 2.4599x over previous
//
#include <hip/hip_runtime.h>

// TopKGate: x[16384,2048] fp32, Wg[2048,64] fp32 ->
//   gate_weights[T,64], top_idx[T,2] (as float), aux_loss (1 float)
//
// 2D-register-tiled GEMM, LDS-free barrier-free main loop.
// Block: 4 waves, 32 tokens, K-split 4 (wave v owns d in [v*512,(v+1)*512)).
// Wave: 8 token-groups x 8 expert-groups; thread tile 4 tok x 8 exp (acc[4][8]).
// x: per-lane float4 VGPR loads (distance-2 prefetch, 4 buffers).
// w: per-lane float4 VGPR loads (distance-1 ping-pong, L2-resident).
// K-partials combined in LDS once; verified softmax/top-2/aux epilogue.

constexpr int DD = 2048;
constexpr int EE = 64;
constexpr int MTOK = 32;              // tokens per block
constexpr int KSPLIT = 4;             // waves per block
constexpr int KSLICE = DD / KSPLIT;   // 512
constexpr int NSUPER = KSLICE / 16;   // 32 superloops of 16 k

__global__ __launch_bounds__(256, 2) void gate_kernel(
    const float* __restrict__ x, const float* __restrict__ Wg,
    float* __restrict__ gate_out, float* __restrict__ idx_out,
    float* __restrict__ pSum, float* __restrict__ pCnt)
{
    const int tid  = threadIdx.x;
    const int wv   = tid >> 6;          // 0..3 (K-slice)
    const int lane = tid & 63;
    const int tg   = lane >> 3;         // token group 0..7
    const int eg   = lane & 7;          // expert group 0..7
    const size_t tok0 = (size_t)blockIdx.x * MTOK;
    const int kbase = wv * KSLICE;

    float acc[4][8];
#pragma unroll
    for (int i = 0; i < 4; ++i)
#pragma unroll
        for (int j = 0; j < 8; ++j) acc[i][j] = 0.f;

    float4 xq[4][4];   // [buf][row]  : x[tok][k..k+4), distance-2 prefetch
    float4 wq[2][8];   // [buf][2k+h] : w[k][e0+4h..+4), distance-1 ping-pong

    const float* xr[4];
#pragma unroll
    for (int i = 0; i < 4; ++i)
        xr[i] = x + (tok0 + tg * 4 + i) * DD + kbase;
    const float* wp = Wg + (size_t)kbase * EE + eg * 8;

    // ---- prologue: xq[0](k0), xq[1](k4), wq[0](k0..4) ----
#pragma unroll
    for (int i = 0; i < 4; ++i) xq[0][i] = *(const float4*)(xr[i] + 0);
#pragma unroll
    for (int i = 0; i < 4; ++i) xq[1][i] = *(const float4*)(xr[i] + 4);
#pragma unroll
    for (int kk = 0; kk < 4; ++kk)
#pragma unroll
        for (int h = 0; h < 2; ++h)
            wq[0][2 * kk + h] = *(const float4*)(wp + kk * EE + h * 4);

    // body B: prefetch xq[(B+2)&3] (k+8), wq[(B+1)&1] (k+4); compute 128 FMAs
#define BODY(B, PFX, PFW)                                                      \
    do {                                                                       \
        if (PFX) {                                                             \
            _Pragma("unroll")                                                  \
            for (int i = 0; i < 4; ++i)                                        \
                xq[((B) + 2) & 3][i] = *(const float4*)(xr[i] + ((B) + 2) * 4);\
        }                                                                      \
        if (PFW) {                                                             \
            _Pragma("unroll")                                                  \
            for (int kk = 0; kk < 4; ++kk)                                     \
                _Pragma("unroll")                                              \
                for (int h = 0; h < 2; ++h)                                    \
                    wq[((B) + 1) & 1][2 * kk + h] =                            \
                        *(const float4*)(wp + 256 + kk * EE + h * 4);          \
        }                                                                      \
        _Pragma("unroll")                                                      \
        for (int kk = 0; kk < 4; ++kk)                                         \
            _Pragma("unroll")                                                  \
            for (int i = 0; i < 4; ++i) {                                      \
                const float xs = ((const float*)&xq[(B) & 3][i])[kk];          \
                _Pragma("unroll")                                              \
                for (int h = 0; h < 2; ++h)                                    \
                    _Pragma("unroll")                                          \
                    for (int j = 0; j < 4; ++j)                                \
                        acc[i][h * 4 + j] = fmaf(                              \
                            xs, ((const float*)&wq[(B) & 1][2 * kk + h])[j],   \
                            acc[i][h * 4 + j]);                                \
            }                                                                  \
        wp += 256;                                                             \
    } while (0)

#pragma unroll 1
    for (int s = 0; s < NSUPER - 1; ++s) {
        BODY(0, 1, 1);
        BODY(1, 1, 1);
        BODY(2, 1, 1);
        BODY(3, 1, 1);
#pragma unroll
        for (int i = 0; i < 4; ++i) xr[i] += 16;
    }
    // final superloop: skip out-of-slice prefetches (no OOB reads)
    BODY(0, 1, 1);
    BODY(1, 1, 1);
    BODY(2, 0, 1);
    BODY(3, 0, 0);
#undef BODY

    // ---- combine K-partials in LDS: red[w][t][e], pad 68 (16B-aligned rows) ----
    __shared__ __align__(16) float red[KSPLIT][MTOK][68];
#pragma unroll
    for (int i = 0; i < 4; ++i) {
        float4 lo = make_float4(acc[i][0], acc[i][1], acc[i][2], acc[i][3]);
        float4 hi = make_float4(acc[i][4], acc[i][5], acc[i][6], acc[i][7]);
        *(float4*)&red[wv][tg * 4 + i][eg * 8]     = lo;
        *(float4*)&red[wv][tg * 4 + i][eg * 8 + 4] = hi;
    }
    __syncthreads();

    // ---- epilogue: wave wv handles tokens [wv*8, wv*8+8); lane = expert ----
    float sumP_acc = 0.f;
    float cnt_acc  = 0.f;
#pragma unroll 1
    for (int tt = 0; tt < 8; ++tt) {
        const int tl = wv * 8 + tt;
        const size_t t = tok0 + tl;
        float v = red[0][tl][lane] + red[1][tl][lane]
                + red[2][tl][lane] + red[3][tl][lane];

        float m = v;
#pragma unroll
        for (int off = 32; off; off >>= 1) m = fmaxf(m, __shfl_xor(m, off, 64));
        float p = expf(v - m);
        float s = p;
#pragma unroll
        for (int off = 32; off; off >>= 1) s += __shfl_xor(s, off, 64);
        float prob = p / s;
        sumP_acc += prob;

        // top-1 (ties -> lowest index, matches lax.top_k)
        float bv = prob; int bi = lane;
#pragma unroll
        for (int off = 32; off; off >>= 1) {
            float ov = __shfl_xor(bv, off, 64);
            int   oi = __shfl_xor(bi, off, 64);
            if (ov > bv || (ov == bv && oi < bi)) { bv = ov; bi = oi; }
        }
        // top-2
        float v2 = (lane == bi) ? -1.f : prob;
        float bv2 = v2; int bi2 = lane;
#pragma unroll
        for (int off = 32; off; off >>= 1) {
            float ov = __shfl_xor(bv2, off, 64);
            int   oi = __shfl_xor(bi2, off, 64);
            if (ov > bv2 || (ov == bv2 && oi < bi2)) { bv2 = ov; bi2 = oi; }
        }

        float denom = bv + bv2;
        float g1 = bv / denom, g2 = bv2 / denom;
        float g = (lane == bi) ? g1 : ((lane == bi2) ? g2 : 0.f);
        gate_out[t * EE + lane] = g;
        if (lane == 0) {
            idx_out[2 * t]     = (float)bi;
            idx_out[2 * t + 1] = (float)bi2;
        }
        cnt_acc += (lane == bi)  ? 1.f : 0.f;
        cnt_acc += (lane == bi2) ? 1.f : 0.f;
    }

    // ---- per-block aux partials (deterministic) ----
    __shared__ float auxsm[2][KSPLIT][64];
    auxsm[0][wv][lane] = sumP_acc;
    auxsm[1][wv][lane] = cnt_acc;
    __syncthreads();
    if (wv == 0) {
        float sp = 0.f, c = 0.f;
#pragma unroll
        for (int w = 0; w < KSPLIT; ++w) {
            sp += auxsm[0][w][lane];
            c  += auxsm[1][w][lane];
        }
        pSum[(size_t)blockIdx.x * 64 + lane] = sp;
        pCnt[(size_t)blockIdx.x * 64 + lane] = c;
    }
}

// parallel aux reduction: 1024 threads (16 waves), 4-deep ILP + LDS reduce
__global__ __launch_bounds__(1024) void aux_kernel(
    const float* __restrict__ pSum, const float* __restrict__ pCnt,
    float* __restrict__ aux_out, int nblocks, float scale)
{
    const int tid  = threadIdx.x;
    const int wv   = tid >> 6;       // 0..15
    const int lane = tid & 63;       // = expert id
    __shared__ float smem[2][16][64];

    float sp[4] = {0.f, 0.f, 0.f, 0.f};
    float cc[4] = {0.f, 0.f, 0.f, 0.f};
    for (int b = wv * 4; b < nblocks; b += 64) {
#pragma unroll
        for (int u = 0; u < 4; ++u) {
            sp[u] += pSum[(size_t)(b + u) * 64 + lane];
            cc[u] += pCnt[(size_t)(b + u) * 64 + lane];
        }
    }
    smem[0][wv][lane] = (sp[0] + sp[1]) + (sp[2] + sp[3]);
    smem[1][wv][lane] = (cc[0] + cc[1]) + (cc[2] + cc[3]);
    __syncthreads();
    if (wv == 0) {
        float SP = 0.f, C = 0.f;
#pragma unroll
        for (int w = 0; w < 16; ++w) {
            SP += smem[0][w][lane];
            C  += smem[1][w][lane];
        }
        float prod = SP * C;
#pragma unroll
        for (int off = 32; off; off >>= 1) prod += __shfl_xor(prod, off, 64);
        if (lane == 0) aux_out[0] = prod * scale;
    }
}

extern "C" void kernel_launch(void* const* d_in, const int* in_sizes, int n_in,
                              void* d_out, int out_size, void* d_ws, size_t ws_size,
                              hipStream_t stream) {
    const float* x  = (const float*)d_in[0];
    const float* Wg = (const float*)d_in[1];
    const int T = in_sizes[0] / DD;          // 16384

    float* out      = (float*)d_out;
    float* gate_out = out;                                // T*64
    float* idx_out  = out + (size_t)T * EE;               // T*2 (as float)
    float* aux_out  = idx_out + (size_t)T * 2;            // 1

    const int nblocks = T / MTOK;                         // 512
    float* pSum = (float*)d_ws;                           // nblocks*64
    float* pCnt = pSum + (size_t)nblocks * 64;            // nblocks*64

    gate_kernel<<<nblocks, 256, 0, stream>>>(x, Wg, gate_out, idx_out, pSum, pCnt);

    const float scale = (float)EE / ((float)T * (float)T);
    aux_kernel<<<1, 1024, 0, stream>>>(pSum, pCnt, aux_out, nblocks, scale);
}